// Round 1
// 903.771 us; speedup vs baseline: 1.1652x; 1.1652x over previous
//
#include <hip/hip_runtime.h>
#include <hip/hip_bf16.h>
#include <stdint.h>

// Problem constants (reference: N=16384, C_IN=4096, C_OUT=4096, fp32, y = x @ W^T + b)
#define NROWS 16384
#define KDIM  4096
#define COUT  4096

// 256x256 tile, BK=64, 8 waves (2M x 4N), double-buffered 128 KiB LDS.
#define BM 256
#define BN 256
#define BK 64
#define NT (KDIM / BK)          // 64 K-tiles
#define NBLK ((NROWS / BM) * (COUT / BN))   // 64*16 = 1024 workgroups

typedef float f32x4 __attribute__((ext_vector_type(4)));
typedef __bf16 bf16x8 __attribute__((ext_vector_type(8)));

// ---------------------------------------------------------------------------
// fp32 -> bf16 (RNE) converter, 4 elements/thread, fully coalesced.
// ---------------------------------------------------------------------------
__device__ __forceinline__ unsigned pack_bf16x2(float x, float y) {
    unsigned a = __builtin_bit_cast(unsigned, x);
    unsigned b = __builtin_bit_cast(unsigned, y);
    a = (a + 0x7fffu + ((a >> 16) & 1u)) >> 16;   // round-to-nearest-even
    b = (b + 0x7fffu + ((b >> 16) & 1u)) >> 16;
    return a | (b << 16);
}

__global__ __launch_bounds__(256) void cvt_f32_to_bf16(
    const float4* __restrict__ in, uint2* __restrict__ out, int n4) {
    int i = blockIdx.x * blockDim.x + threadIdx.x;
    if (i >= n4) return;
    float4 a = in[i];
    uint2 o;
    o.x = pack_bf16x2(a.x, a.y);
    o.y = pack_bf16x2(a.z, a.w);
    out[i] = o;
}

// ---------------------------------------------------------------------------
// Async global->LDS, 16B per lane. LDS dest is wave-uniform base + lane*16.
// ---------------------------------------------------------------------------
__device__ __forceinline__ void async16(const void* g, const void* l) {
    __builtin_amdgcn_global_load_lds(
        reinterpret_cast<const unsigned __attribute__((address_space(1)))*>(
            reinterpret_cast<uintptr_t>(g)),
        reinterpret_cast<unsigned __attribute__((address_space(3)))*>(
            reinterpret_cast<uintptr_t>(l)),   // low 32 bits = LDS offset
        16, 0, 0);
}

// ---------------------------------------------------------------------------
// 256x256 8-phase counted-vmcnt GEMM (m201-template port, BK=64).
// C[m][n] = sum_k A[m][k]*B[n][k] + bias[n]; A: NROWS x K, B: COUT x K (bf16).
//
// LDS layout per operand: [2 buf][256 rows][8 chunks of 16B]; chunk slot for
// (row, k-chunk c) is c ^ (row&7). global_load_lds dest stays linear; lanes
// fetch the permuted global chunk instead (both-sides involution, rule 21).
// ds_read_b128 frag reads then spread each 16-lane phase across all 8
// four-bank groups at 2 lanes each -> conflict-free (same family as the
// verified R1 swizzle, extended to 128B rows).
//
// Per K-tile, 4 phases (quadrant walk A0B0 -> A0B1 -> A1B1 -> A1B0 so the
// 4 A-frags are register-reused across halves):
//   ph0: ds_read a[0..3]+b0 (12) | stage A0(t+1)->nxt | bar | lgkm0 | 16 MFMA | bar
//   ph1: ds_read b1 (4)         | stage A1(t+1)->nxt | bar | lgkm0 | 16 MFMA | bar
//   ph2: ds_read a[4..7] (8)    | stage B0(t+2)->cur | bar | lgkm0 | 16 MFMA | bar
//   ph3:                          stage B1(t+2)->cur |       16 MFMA | vmcnt(4) | bar
// B(t+2) may write buf[cur] because B's last LDS read is ph1 (lgkm'd before
// the ph1-end barrier). Boundary vmcnt(4) keeps B(t+2)'s 4 loads in flight
// (counted, never 0 in steady state -- T4); vmcnt(0) only at the last tile.
// ---------------------------------------------------------------------------
__global__ __launch_bounds__(512, 2) void gemm_bt_bf16_8ph(
    const short* __restrict__ A,     // NROWS x KDIM (bf16 bits)
    const short* __restrict__ B,     // COUT  x KDIM (bf16 bits)
    const float* __restrict__ bias,  // COUT
    float* __restrict__ C) {         // NROWS x COUT
    __shared__ alignas(16) short As[2 * BM * BK];   // 64 KiB
    __shared__ alignas(16) short Bs[2 * BN * BK];   // 64 KiB

    const int tid  = threadIdx.x;
    const int wave = tid >> 6;
    const int lane = tid & 63;

    // XCD-aware swizzle (T1): 1024 wgs, 1024 % 8 == 0 -> bijective.
    const int bid = blockIdx.x;
    const int sid = (bid & 7) * (NBLK / 8) + (bid >> 3);
    const int block_m = (sid >> 4) * BM;   // 64 m-tiles
    const int block_n = (sid & 15) * BN;   // 16 n-tiles

    // --- staging addressing (pre-swizzled global source, linear LDS dest) ---
    const int r0 = tid >> 3;                        // 0..63: row within 64-row load
    const int sc = (lane & 7) ^ ((lane >> 3) & 7);  // global chunk this lane fetches
    const short* aG = A + (size_t)(block_m + r0) * KDIM + sc * 8;
    const short* bG = B + (size_t)(block_n + r0) * KDIM + sc * 8;

    auto stageA = [&](int buf, int tt, int h) {
        const short* g = aG + ((size_t)h * 128) * KDIM + (size_t)tt * BK;
        const short* l = (const short*)As + buf * 16384 + h * 8192 + wave * 512;
        async16(g, l);                               // rows h*128 + [0,64)
        async16(g + (size_t)64 * KDIM, l + 4096);    // rows h*128 + [64,128)
    };
    auto stageB = [&](int buf, int tt, int h) {
        const short* g = bG + ((size_t)h * 128) * KDIM + (size_t)tt * BK;
        const short* l = (const short*)Bs + buf * 16384 + h * 8192 + wave * 512;
        async16(g, l);
        async16(g + (size_t)64 * KDIM, l + 4096);
    };

    // --- fragment addressing -------------------------------------------------
    const int wm = wave >> 2;          // 0..1: 128-row half of the M-tile
    const int wn = wave & 3;           // 0..3: 64-col slice of the N-tile
    const int fr = lane & 15;          // element row within 16x16 frag
    const int fq = lane >> 4;          // k-chunk 0..3 within a K=32 group
    const int fx = fr & 7;             // swizzle key

    auto lda4 = [&](bf16x8 (&f)[4][2], const short* base, int i0) {
#pragma unroll
        for (int i = 0; i < 4; ++i)
#pragma unroll
            for (int s = 0; s < 2; ++s)
                f[i][s] = *reinterpret_cast<const bf16x8*>(
                    base + (wm * 128 + (i0 + i) * 16 + fr) * 64 +
                    ((s * 4 + fq) ^ fx) * 8);
    };
    auto ldb2 = [&](bf16x8 (&f)[2][2], const short* base, int j0) {
#pragma unroll
        for (int j = 0; j < 2; ++j)
#pragma unroll
            for (int s = 0; s < 2; ++s)
                f[j][s] = *reinterpret_cast<const bf16x8*>(
                    base + (wn * 64 + (j0 + j) * 16 + fr) * 64 +
                    ((s * 4 + fq) ^ fx) * 8);
    };

    f32x4 acc[8][4] = {};

    auto mfma8 = [&](bf16x8 (&a)[4][2], bf16x8 (&b)[2][2], int i0, int j0) {
#pragma unroll
        for (int i = 0; i < 4; ++i)
#pragma unroll
            for (int j = 0; j < 2; ++j)
#pragma unroll
                for (int s = 0; s < 2; ++s)
                    acc[i0 + i][j0 + j] = __builtin_amdgcn_mfma_f32_16x16x32_bf16(
                        a[i][s], b[j][s], acc[i0 + i][j0 + j], 0, 0, 0);
    };

    bf16x8 af[4][2], fb0[2][2], fb1[2][2];

    // --- prologue: tile 0 (all 4 halves) + B halves of tile 1 ---------------
    stageA(0, 0, 0); stageA(0, 0, 1);
    stageB(0, 0, 0); stageB(0, 0, 1);
    stageB(1, 1, 0); stageB(1, 1, 1);
    asm volatile("s_waitcnt vmcnt(4)" ::: "memory");   // tile 0 landed, B(1) in flight
    __builtin_amdgcn_s_barrier();
    __builtin_amdgcn_sched_barrier(0);

#pragma unroll 1
    for (int t = 0; t < NT; ++t) {
        const int cur = t & 1, nxt = cur ^ 1;
        const short* Ac = (const short*)As + cur * 16384;
        const short* Bc = (const short*)Bs + cur * 16384;

        // ---- phase 0: quadrant (i 0-3, j 0-1) ----
        lda4(af, Ac, 0);
        ldb2(fb0, Bc, 0);
        if (t + 1 < NT) stageA(nxt, t + 1, 0);
        __builtin_amdgcn_s_barrier();
        asm volatile("s_waitcnt lgkmcnt(0)" ::: "memory");
        __builtin_amdgcn_sched_barrier(0);
        __builtin_amdgcn_s_setprio(1);
        mfma8(af, fb0, 0, 0);
        __builtin_amdgcn_s_setprio(0);
        __builtin_amdgcn_s_barrier();

        // ---- phase 1: quadrant (i 0-3, j 2-3) ----
        ldb2(fb1, Bc, 2);
        if (t + 1 < NT) stageA(nxt, t + 1, 1);
        __builtin_amdgcn_s_barrier();
        asm volatile("s_waitcnt lgkmcnt(0)" ::: "memory");
        __builtin_amdgcn_sched_barrier(0);
        __builtin_amdgcn_s_setprio(1);
        mfma8(af, fb1, 0, 2);
        __builtin_amdgcn_s_setprio(0);
        __builtin_amdgcn_s_barrier();

        // ---- phase 2: quadrant (i 4-7, j 2-3); af registers reused ----
        lda4(af, Ac, 4);
        if (t + 2 < NT) stageB(cur, t + 2, 0);   // B last read was ph1 -> safe
        __builtin_amdgcn_s_barrier();
        asm volatile("s_waitcnt lgkmcnt(0)" ::: "memory");
        __builtin_amdgcn_sched_barrier(0);
        __builtin_amdgcn_s_setprio(1);
        mfma8(af, fb1, 4, 2);
        __builtin_amdgcn_s_setprio(0);
        __builtin_amdgcn_s_barrier();

        // ---- phase 3: quadrant (i 4-7, j 0-1); tile boundary ----
        if (t + 2 < NT) stageB(cur, t + 2, 1);
        __builtin_amdgcn_s_setprio(1);
        mfma8(af, fb0, 4, 0);                    // regs only, no new reads
        __builtin_amdgcn_s_setprio(0);
        if (t < NT - 1) {
            if (t < NT - 2) asm volatile("s_waitcnt vmcnt(4)" ::: "memory");
            else            asm volatile("s_waitcnt vmcnt(0)" ::: "memory");
            __builtin_amdgcn_s_barrier();
            __builtin_amdgcn_sched_barrier(0);
        }
    }

    // --- epilogue: C/D layout col=lane&15, row=(lane>>4)*4+reg (m89/m91) ----
    const int cm = block_m + wm * 128 + (lane >> 4) * 4;
    const int cn = block_n + wn * 64 + (lane & 15);
#pragma unroll
    for (int j = 0; j < 4; ++j) {
        const float bj = bias[cn + j * 16];
#pragma unroll
        for (int i = 0; i < 8; ++i) {
#pragma unroll
            for (int r = 0; r < 4; ++r) {
                C[(size_t)(cm + i * 16 + r) * COUT + (cn + j * 16)] =
                    acc[i][j][r] + bj;
            }
        }
    }
}

// ---------------------------------------------------------------------------
extern "C" void kernel_launch(void* const* d_in, const int* in_sizes, int n_in,
                              void* d_out, int out_size, void* d_ws, size_t ws_size,
                              hipStream_t stream) {
    const float* x    = (const float*)d_in[0];   // NROWS x KDIM
    const float* w    = (const float*)d_in[1];   // COUT  x KDIM
    const float* bias = (const float*)d_in[2];   // COUT
    float* out = (float*)d_out;

    // workspace layout: xb (134.2 MB) | wb (33.6 MB)
    short* xb = (short*)d_ws;
    short* wb = xb + (size_t)NROWS * KDIM;

    const int n4_x = NROWS * (KDIM / 4);   // 16777216
    const int n4_w = COUT  * (KDIM / 4);   // 4194304

    cvt_f32_to_bf16<<<n4_x / 256, 256, 0, stream>>>(
        (const float4*)x, (uint2*)xb, n4_x);
    cvt_f32_to_bf16<<<n4_w / 256, 256, 0, stream>>>(
        (const float4*)w, (uint2*)wb, n4_w);

    dim3 grid(NBLK);   // 1024 blocks of 512 threads
    gemm_bt_bf16_8ph<<<grid, 512, 0, stream>>>(xb, wb, bias, out);
}

// Round 2
// 902.048 us; speedup vs baseline: 1.1674x; 1.0019x over previous
//
#include <hip/hip_runtime.h>
#include <hip/hip_bf16.h>
#include <stdint.h>

// Problem constants (reference: N=16384, C_IN=4096, C_OUT=4096, fp32, y = x @ W^T + b)
#define NROWS 16384
#define KDIM  4096
#define COUT  4096

// 256x256 tile, BK=64, 8 waves (2M x 4N), double-buffered 128 KiB LDS.
#define BM 256
#define BN 256
#define BK 64
#define NT (KDIM / BK)          // 64 K-tiles
#define NBLK ((NROWS / BM) * (COUT / BN))   // 64*16 = 1024 workgroups

typedef float f32x4 __attribute__((ext_vector_type(4)));
typedef __bf16 bf16x8 __attribute__((ext_vector_type(8)));

// ---------------------------------------------------------------------------
// fp32 -> bf16 (RNE) converter, 4 elements/thread, fully coalesced.
// ---------------------------------------------------------------------------
__device__ __forceinline__ unsigned pack_bf16x2(float x, float y) {
    unsigned a = __builtin_bit_cast(unsigned, x);
    unsigned b = __builtin_bit_cast(unsigned, y);
    a = (a + 0x7fffu + ((a >> 16) & 1u)) >> 16;   // round-to-nearest-even
    b = (b + 0x7fffu + ((b >> 16) & 1u)) >> 16;
    return a | (b << 16);
}

__global__ __launch_bounds__(256) void cvt_f32_to_bf16(
    const float4* __restrict__ in, uint2* __restrict__ out, int n4) {
    int i = blockIdx.x * blockDim.x + threadIdx.x;
    if (i >= n4) return;
    float4 a = in[i];
    uint2 o;
    o.x = pack_bf16x2(a.x, a.y);
    o.y = pack_bf16x2(a.z, a.w);
    out[i] = o;
}

// ---------------------------------------------------------------------------
// Async global->LDS, 16B per lane. LDS dest is wave-uniform base + lane*16.
// ---------------------------------------------------------------------------
__device__ __forceinline__ void async16(const void* g, const void* l) {
    __builtin_amdgcn_global_load_lds(
        reinterpret_cast<const unsigned __attribute__((address_space(1)))*>(
            reinterpret_cast<uintptr_t>(g)),
        reinterpret_cast<unsigned __attribute__((address_space(3)))*>(
            reinterpret_cast<uintptr_t>(l)),   // low 32 bits = LDS offset
        16, 0, 0);
}

// ---------------------------------------------------------------------------
// 256x256 8-phase counted-vmcnt GEMM, revision 2:
//  - 2 K-tiles unrolled per loop iter -> static LDS buffer addressing
//  - deep symmetric prefetch: tile t+2's B staged in ph2(t), A in ph3(t);
//    steady-state boundary wait vmcnt(8) (tile t+2's loads stay in flight,
//    tile t+1 guaranteed landed). vmcnt(0) only at the NT-2 edge.
//  - fb1's 4 ds_reads issued in ph0 with counted lgkmcnt(4); ph1 is wait-free
//  - MFMA K-chunk outermost (no dependent back-to-back MFMA pairs)
//
// Hazard derivation (sync-structure edit; re-verified):
//  * B-reads of tile t finish (per-wave lgkm) before ph1's MFMA; the ph1-end
//    barrier then orders all waves before ph2's stageB(p, t+2) write to the
//    same buffer. A-reads finish before ph2's MFMA; ph2-end barrier orders
//    them before ph3's stageA(p, t+2).
//  * Tile t+2 targets buf p (= tile t's buffer); nothing reads buf p during
//    tile t+1; reads resume at tile t+2 ph0, after the boundary vmcnt+barrier.
//  * Boundary of tile t needs tile t+1 landed; the only younger VMEM ops are
//    tile t+2's 8 loads (if staged) -> vmcnt(8), else vmcnt(0).
//
// LDS layout per operand: [2 buf][256 rows][8 chunks of 16B]; slot s of row r
// holds global chunk s ^ (r&7) (both-sides involution; linear gload_lds dest,
// pre-swizzled global source). Frag reads spread evenly over all 8 four-bank
// groups (8 lanes/group = wave64 minimum) -> conflict-free (measured 0).
// ---------------------------------------------------------------------------
__global__ __launch_bounds__(512, 2) void gemm_bt_bf16_8ph(
    const short* __restrict__ A,     // NROWS x KDIM (bf16 bits)
    const short* __restrict__ B,     // COUT  x KDIM (bf16 bits)
    const float* __restrict__ bias,  // COUT
    float* __restrict__ C) {         // NROWS x COUT
    __shared__ alignas(16) short As[2 * BM * BK];   // 64 KiB
    __shared__ alignas(16) short Bs[2 * BN * BK];   // 64 KiB

    const int tid  = threadIdx.x;
    const int wave = tid >> 6;
    const int lane = tid & 63;

    // XCD-aware swizzle (T1): 1024 wgs, 1024 % 8 == 0 -> bijective.
    const int bid = blockIdx.x;
    const int sid = (bid & 7) * (NBLK / 8) + (bid >> 3);
    const int block_m = (sid >> 4) * BM;   // 64 m-tiles
    const int block_n = (sid & 15) * BN;   // 16 n-tiles

    // --- staging addressing (pre-swizzled global source, linear LDS dest) ---
    const int r0 = tid >> 3;                        // 0..63: row within 64-row load
    const int sc = (lane & 7) ^ ((lane >> 3) & 7);  // global chunk this lane fetches
    const short* aG = A + (size_t)(block_m + r0) * KDIM + sc * 8;
    const short* bG = B + (size_t)(block_n + r0) * KDIM + sc * 8;

    auto stageA = [&](int buf, int tt, int h) {
        const short* g = aG + ((size_t)h * 128) * KDIM + (size_t)tt * BK;
        const short* l = (const short*)As + buf * 16384 + h * 8192 + wave * 512;
        async16(g, l);                               // rows h*128 + [0,64)
        async16(g + (size_t)64 * KDIM, l + 4096);    // rows h*128 + [64,128)
    };
    auto stageB = [&](int buf, int tt, int h) {
        const short* g = bG + ((size_t)h * 128) * KDIM + (size_t)tt * BK;
        const short* l = (const short*)Bs + buf * 16384 + h * 8192 + wave * 512;
        async16(g, l);
        async16(g + (size_t)64 * KDIM, l + 4096);
    };

    // --- fragment addressing -------------------------------------------------
    const int wm = wave >> 2;          // 0..1: 128-row half of the M-tile
    const int wn = wave & 3;           // 0..3: 64-col slice of the N-tile
    const int fr = lane & 15;          // element row within 16x16 frag
    const int fq = lane >> 4;          // k-chunk 0..3 within a K=32 group
    const int fx = fr & 7;             // swizzle key

    auto lda4 = [&](bf16x8 (&f)[4][2], const short* base, int i0) {
#pragma unroll
        for (int i = 0; i < 4; ++i)
#pragma unroll
            for (int s = 0; s < 2; ++s)
                f[i][s] = *reinterpret_cast<const bf16x8*>(
                    base + (wm * 128 + (i0 + i) * 16 + fr) * 64 +
                    ((s * 4 + fq) ^ fx) * 8);
    };
    auto ldb2 = [&](bf16x8 (&f)[2][2], const short* base, int j0) {
#pragma unroll
        for (int j = 0; j < 2; ++j)
#pragma unroll
            for (int s = 0; s < 2; ++s)
                f[j][s] = *reinterpret_cast<const bf16x8*>(
                    base + (wn * 64 + (j0 + j) * 16 + fr) * 64 +
                    ((s * 4 + fq) ^ fx) * 8);
    };

    f32x4 acc[8][4] = {};

    // K-chunk outermost: 8 independent MFMAs per s-group, dependent pair
    // spacing = 8 MFMAs (~40 cyc) instead of back-to-back.
    auto mfma8 = [&](bf16x8 (&a)[4][2], bf16x8 (&b)[2][2], int i0, int j0) {
#pragma unroll
        for (int s = 0; s < 2; ++s)
#pragma unroll
            for (int i = 0; i < 4; ++i)
#pragma unroll
                for (int j = 0; j < 2; ++j)
                    acc[i0 + i][j0 + j] = __builtin_amdgcn_mfma_f32_16x16x32_bf16(
                        a[i][s], b[j][s], acc[i0 + i][j0 + j], 0, 0, 0);
    };

    bf16x8 af[4][2], fb0[2][2], fb1[2][2];

    // One K-tile = 4 phases. Ac/Bc are compile-time-static per unrolled half.
    auto tile_body = [&](int t, const short* Ac, const short* Bc, int buf) {
        // ---- phase 0: quadrant (i 0-3, j 0-1); issue fb1 early ----
        lda4(af, Ac, 0);
        ldb2(fb0, Bc, 0);
        __builtin_amdgcn_sched_barrier(0);   // pin issue order for counted lgkm
        ldb2(fb1, Bc, 2);
        __builtin_amdgcn_s_barrier();
        asm volatile("s_waitcnt lgkmcnt(4)" ::: "memory");   // af+fb0 landed; fb1 in flight
        __builtin_amdgcn_sched_barrier(0);
        __builtin_amdgcn_s_setprio(1);
        mfma8(af, fb0, 0, 0);
        __builtin_amdgcn_s_setprio(0);
        __builtin_amdgcn_s_barrier();

        // ---- phase 1: quadrant (i 0-3, j 2-3); wait-free (fb1 prefetched) ----
        asm volatile("s_waitcnt lgkmcnt(0)" ::: "memory");
        __builtin_amdgcn_sched_barrier(0);
        __builtin_amdgcn_s_setprio(1);
        mfma8(af, fb1, 0, 2);
        __builtin_amdgcn_s_setprio(0);
        __builtin_amdgcn_s_barrier();

        // ---- phase 2: quadrant (i 4-7, j 2-3); stage B(t+2) -> same buf ----
        lda4(af, Ac, 4);
        if (t + 2 < NT) { stageB(buf, t + 2, 0); stageB(buf, t + 2, 1); }
        __builtin_amdgcn_s_barrier();
        asm volatile("s_waitcnt lgkmcnt(0)" ::: "memory");
        __builtin_amdgcn_sched_barrier(0);
        __builtin_amdgcn_s_setprio(1);
        mfma8(af, fb1, 4, 2);
        __builtin_amdgcn_s_setprio(0);
        __builtin_amdgcn_s_barrier();

        // ---- phase 3: quadrant (i 4-7, j 0-1); stage A(t+2) -> same buf ----
        if (t + 2 < NT) { stageA(buf, t + 2, 0); stageA(buf, t + 2, 1); }
        __builtin_amdgcn_s_setprio(1);
        mfma8(af, fb0, 4, 0);                    // regs only, no new reads
        __builtin_amdgcn_s_setprio(0);
    };

    // --- prologue: tiles 0 and 1 fully staged (16 loads) --------------------
    stageA(0, 0, 0); stageA(0, 0, 1); stageB(0, 0, 0); stageB(0, 0, 1);
    stageA(1, 1, 0); stageA(1, 1, 1); stageB(1, 1, 0); stageB(1, 1, 1);
    asm volatile("s_waitcnt vmcnt(8)" ::: "memory");   // tile0 landed, tile1 in flight
    __builtin_amdgcn_s_barrier();
    __builtin_amdgcn_sched_barrier(0);

    const short* As0 = (const short*)As;
    const short* As1 = (const short*)As + 16384;
    const short* Bs0 = (const short*)Bs;
    const short* Bs1 = (const short*)Bs + 16384;

#pragma unroll 1
    for (int t = 0; t < NT; t += 2) {
        tile_body(t, As0, Bs0, 0);
        // boundary after even tile t: need tile t+1 landed;
        // younger VMEM = tile t+2's 8 loads (if staged).
        if (t + 2 < NT) asm volatile("s_waitcnt vmcnt(8)" ::: "memory");
        else            asm volatile("s_waitcnt vmcnt(0)" ::: "memory");
        __builtin_amdgcn_s_barrier();
        __builtin_amdgcn_sched_barrier(0);

        tile_body(t + 1, As1, Bs1, 1);
        if (t + 2 < NT) {
            // boundary after odd tile t+1: need tile t+2 landed;
            // younger VMEM = tile t+3's 8 loads (if staged).
            if (t + 3 < NT) asm volatile("s_waitcnt vmcnt(8)" ::: "memory");
            else            asm volatile("s_waitcnt vmcnt(0)" ::: "memory");
            __builtin_amdgcn_s_barrier();
            __builtin_amdgcn_sched_barrier(0);
        }
    }

    // --- epilogue: C/D layout col=lane&15, row=(lane>>4)*4+reg (m89/m91) ----
    const int cm = block_m + wm * 128 + (lane >> 4) * 4;
    const int cn = block_n + wn * 64 + (lane & 15);
#pragma unroll
    for (int j = 0; j < 4; ++j) {
        const float bj = bias[cn + j * 16];
#pragma unroll
        for (int i = 0; i < 8; ++i) {
#pragma unroll
            for (int r = 0; r < 4; ++r) {
                C[(size_t)(cm + i * 16 + r) * COUT + (cn + j * 16)] =
                    acc[i][j][r] + bj;
            }
        }
    }
}

// ---------------------------------------------------------------------------
extern "C" void kernel_launch(void* const* d_in, const int* in_sizes, int n_in,
                              void* d_out, int out_size, void* d_ws, size_t ws_size,
                              hipStream_t stream) {
    const float* x    = (const float*)d_in[0];   // NROWS x KDIM
    const float* w    = (const float*)d_in[1];   // COUT  x KDIM
    const float* bias = (const float*)d_in[2];   // COUT
    float* out = (float*)d_out;

    // workspace layout: xb (134.2 MB) | wb (33.6 MB)
    short* xb = (short*)d_ws;
    short* wb = xb + (size_t)NROWS * KDIM;

    const int n4_x = NROWS * (KDIM / 4);   // 16777216
    const int n4_w = COUT  * (KDIM / 4);   // 4194304

    cvt_f32_to_bf16<<<n4_x / 256, 256, 0, stream>>>(
        (const float4*)x, (uint2*)xb, n4_x);
    cvt_f32_to_bf16<<<n4_w / 256, 256, 0, stream>>>(
        (const float4*)w, (uint2*)wb, n4_w);

    dim3 grid(NBLK);   // 1024 blocks of 512 threads
    gemm_bt_bf16_8ph<<<grid, 512, 0, stream>>>(xb, wb, bias, out);
}

// Round 3
// 887.738 us; speedup vs baseline: 1.1862x; 1.0161x over previous
//
#include <hip/hip_runtime.h>
#include <hip/hip_bf16.h>
#include <stdint.h>

// Problem constants (reference: N=16384, C_IN=4096, C_OUT=4096, fp32, y = x @ W^T + b)
#define NROWS 16384
#define KDIM  4096
#define COUT  4096

// 256x256 tile, BK=64, 8 waves (2M x 4N), double-buffered 128 KiB LDS.
#define BM 256
#define BN 256
#define BK 64
#define NT (KDIM / BK)          // 64 K-tiles
#define NBLK ((NROWS / BM) * (COUT / BN))   // 64*16 = 1024 workgroups

typedef float f32x16 __attribute__((ext_vector_type(16)));
typedef __bf16 bf16x8 __attribute__((ext_vector_type(8)));

// ---------------------------------------------------------------------------
// fp32 -> bf16 (RNE) converter, 4 elements/thread, fully coalesced.
// ---------------------------------------------------------------------------
__device__ __forceinline__ unsigned pack_bf16x2(float x, float y) {
    unsigned a = __builtin_bit_cast(unsigned, x);
    unsigned b = __builtin_bit_cast(unsigned, y);
    a = (a + 0x7fffu + ((a >> 16) & 1u)) >> 16;   // round-to-nearest-even
    b = (b + 0x7fffu + ((b >> 16) & 1u)) >> 16;
    return a | (b << 16);
}

__global__ __launch_bounds__(256) void cvt_f32_to_bf16(
    const float4* __restrict__ in, uint2* __restrict__ out, int n4) {
    int i = blockIdx.x * blockDim.x + threadIdx.x;
    if (i >= n4) return;
    float4 a = in[i];
    uint2 o;
    o.x = pack_bf16x2(a.x, a.y);
    o.y = pack_bf16x2(a.z, a.w);
    out[i] = o;
}

// ---------------------------------------------------------------------------
// Async global->LDS, 16B per lane. LDS dest is wave-uniform base + lane*16.
// ---------------------------------------------------------------------------
__device__ __forceinline__ void async16(const void* g, const void* l) {
    __builtin_amdgcn_global_load_lds(
        reinterpret_cast<const unsigned __attribute__((address_space(1)))*>(
            reinterpret_cast<uintptr_t>(g)),
        reinterpret_cast<unsigned __attribute__((address_space(3)))*>(
            reinterpret_cast<uintptr_t>(l)),   // low 32 bits = LDS offset
        16, 0, 0);
}

// ---------------------------------------------------------------------------
// 256x256 GEMM, revision 3: 32x32x16 MFMA + thinned barriers.
//  - v_mfma_f32_32x32x16_bf16: pipe ceiling 2382+ TF vs 2075 for 16x16x32,
//    half the MFMA instruction count. Per-wave 128x64 output = 4x2 tiles of
//    32x32, K-tile = 4 k-groups of 16.
//  - A/B frag: row = lane&31, 8 contiguous k at (lane>>5)*8 (1 ds_read_b128
//    per (tile, kgroup)). C/D: col=lane&31, row=(reg&3)+8*(reg>>2)+4*(lane>>5).
//  - Barriers: 3 per K-tile (only the hazard-required set):
//      ph1-end  (all waves' B-frag reads retired  -> stage B(t+2) into cur)
//      ph2-end  (all waves' A-frag reads retired  -> stage A(t+2) into cur)
//      boundary (vmcnt counted + barrier -> next tile's buffer readable)
//    Pre-MFMA phase-lock barriers dropped: no hazard depends on them; waves
//    drift into natural MFMA||load overlap (m114).
//  - Steady-state bookkeeping (unchanged from refcheck-passed R2): entering
//    tile t, outstanding = t+1's 8 loads; during t we stage t+2's 8; boundary
//    waits vmcnt(8) (=> t+1 landed, t+2 in flight). vmcnt(0) at edge tiles.
//
// LDS layout per operand: [2 buf][256 rows][8 chunks of 16B]; slot s of row r
// holds global chunk s ^ (r&7). Read spread: lanes 0-31 (k-lo) and 32-63
// (k-hi) each cover all 8 slots 4x -> 8 lanes per 16B slot = wave64 optimum.
// ---------------------------------------------------------------------------
__global__ __launch_bounds__(512, 2) void gemm_bt_bf16_8ph(
    const short* __restrict__ A,     // NROWS x KDIM (bf16 bits)
    const short* __restrict__ B,     // COUT  x KDIM (bf16 bits)
    const float* __restrict__ bias,  // COUT
    float* __restrict__ C) {         // NROWS x COUT
    __shared__ alignas(16) short As[2 * BM * BK];   // 64 KiB
    __shared__ alignas(16) short Bs[2 * BN * BK];   // 64 KiB

    const int tid  = threadIdx.x;
    const int wave = tid >> 6;
    const int lane = tid & 63;

    // XCD-aware swizzle (T1): 1024 wgs, 1024 % 8 == 0 -> bijective.
    const int bid = blockIdx.x;
    const int sid = (bid & 7) * (NBLK / 8) + (bid >> 3);
    const int block_m = (sid >> 4) * BM;   // 64 m-tiles
    const int block_n = (sid & 15) * BN;   // 16 n-tiles

    // --- staging addressing (pre-swizzled global source, linear LDS dest) ---
    const int r0 = tid >> 3;                        // 0..63: row within 64-row load
    const int sc = (lane & 7) ^ ((lane >> 3) & 7);  // global chunk this lane fetches
    const short* aG = A + (size_t)(block_m + r0) * KDIM + sc * 8;
    const short* bG = B + (size_t)(block_n + r0) * KDIM + sc * 8;

    auto stageA = [&](int buf, int tt, int h) {
        const short* g = aG + ((size_t)h * 128) * KDIM + (size_t)tt * BK;
        const short* l = (const short*)As + buf * 16384 + h * 8192 + wave * 512;
        async16(g, l);                               // rows h*128 + [0,64)
        async16(g + (size_t)64 * KDIM, l + 4096);    // rows h*128 + [64,128)
    };
    auto stageB = [&](int buf, int tt, int h) {
        const short* g = bG + ((size_t)h * 128) * KDIM + (size_t)tt * BK;
        const short* l = (const short*)Bs + buf * 16384 + h * 8192 + wave * 512;
        async16(g, l);
        async16(g + (size_t)64 * KDIM, l + 4096);
    };

    // --- fragment addressing -------------------------------------------------
    const int wm = wave >> 2;          // 0..1: 128-row half of the M-tile
    const int wn = wave & 3;           // 0..3: 64-col slice of the N-tile
    const int ln31 = lane & 31;        // row/col within a 32x32 tile
    const int lh   = lane >> 5;        // k-half select (k = lh*8 + [0..7])

    // A-frag pair: tiles i0, i0+1; all 4 k-groups. row r, logical chunk
    // kg*2+lh, stored slot = chunk ^ (r&7).
    auto lda2 = [&](bf16x8 (&f)[2][4], const short* base, int i0) {
#pragma unroll
        for (int i = 0; i < 2; ++i) {
            const int r = wm * 128 + (i0 + i) * 32 + ln31;
#pragma unroll
            for (int kg = 0; kg < 4; ++kg)
                f[i][kg] = *reinterpret_cast<const bf16x8*>(
                    base + r * 64 + ((kg * 2 + lh) ^ (r & 7)) * 8);
        }
    };
    // B-frag: tile j; all 4 k-groups.
    auto ldb1 = [&](bf16x8 (&f)[4], const short* base, int j) {
        const int r = wn * 64 + j * 32 + ln31;
#pragma unroll
        for (int kg = 0; kg < 4; ++kg)
            f[kg] = *reinterpret_cast<const bf16x8*>(
                base + r * 64 + ((kg * 2 + lh) ^ (r & 7)) * 8);
    };

    f32x16 acc[4][2] = {};

    // 8 MFMA: tiles (i0, i0+1) x column j, k-groups outermost (dependent
    // accumulate spacing = 2 instrs ~ 68 cyc pipe time).
    auto mfma8 = [&](bf16x8 (&a)[2][4], bf16x8 (&b)[4], int i0, int j) {
#pragma unroll
        for (int kg = 0; kg < 4; ++kg)
#pragma unroll
            for (int i = 0; i < 2; ++i)
                acc[i0 + i][j] = __builtin_amdgcn_mfma_f32_32x32x16_bf16(
                    a[i][kg], b[kg], acc[i0 + i][j], 0, 0, 0);
    };

    bf16x8 af[2][4], fb0[4], fb1[4];

    // One K-tile = 4 phases, quadrant walk (i01,j0)->(i01,j1)->(i23,j1)->(i23,j0).
    auto tile_body = [&](int t, const short* Ac, const short* Bc, int buf) {
        // ---- phase 0: (i01, j0); issue fb1 early, counted lgkm ----
        lda2(af, Ac, 0);
        ldb1(fb0, Bc, 0);
        __builtin_amdgcn_sched_barrier(0);   // pin issue order for counted lgkm
        ldb1(fb1, Bc, 1);
        asm volatile("s_waitcnt lgkmcnt(4)" ::: "memory");   // af+fb0 landed; fb1 in flight
        __builtin_amdgcn_sched_barrier(0);
        __builtin_amdgcn_s_setprio(1);
        mfma8(af, fb0, 0, 0);
        __builtin_amdgcn_s_setprio(0);

        // ---- phase 1: (i01, j1) ----
        asm volatile("s_waitcnt lgkmcnt(0)" ::: "memory");
        __builtin_amdgcn_sched_barrier(0);
        __builtin_amdgcn_s_setprio(1);
        mfma8(af, fb1, 0, 1);
        __builtin_amdgcn_s_setprio(0);
        __builtin_amdgcn_s_barrier();        // REQUIRED: gates stage B(t+2) -> cur

        // ---- phase 2: (i23, j1); stage B(t+2) -> same buf ----
        lda2(af, Ac, 2);
        if (t + 2 < NT) { stageB(buf, t + 2, 0); stageB(buf, t + 2, 1); }
        asm volatile("s_waitcnt lgkmcnt(0)" ::: "memory");
        __builtin_amdgcn_sched_barrier(0);
        __builtin_amdgcn_s_setprio(1);
        mfma8(af, fb1, 2, 1);
        __builtin_amdgcn_s_setprio(0);
        __builtin_amdgcn_s_barrier();        // REQUIRED: gates stage A(t+2) -> cur

        // ---- phase 3: (i23, j0); regs only ----
        if (t + 2 < NT) { stageA(buf, t + 2, 0); stageA(buf, t + 2, 1); }
        __builtin_amdgcn_s_setprio(1);
        mfma8(af, fb0, 2, 0);
        __builtin_amdgcn_s_setprio(0);
    };

    // --- prologue: tiles 0 and 1 fully staged (16 loads) --------------------
    stageA(0, 0, 0); stageA(0, 0, 1); stageB(0, 0, 0); stageB(0, 0, 1);
    stageA(1, 1, 0); stageA(1, 1, 1); stageB(1, 1, 0); stageB(1, 1, 1);
    asm volatile("s_waitcnt vmcnt(8)" ::: "memory");   // tile0 landed, tile1 in flight
    __builtin_amdgcn_s_barrier();
    __builtin_amdgcn_sched_barrier(0);

    const short* As0 = (const short*)As;
    const short* As1 = (const short*)As + 16384;
    const short* Bs0 = (const short*)Bs;
    const short* Bs1 = (const short*)Bs + 16384;

#pragma unroll 1
    for (int t = 0; t < NT; t += 2) {
        tile_body(t, As0, Bs0, 0);
        // boundary after even tile t: need tile t+1 landed;
        // younger VMEM = tile t+2's 8 loads (if staged).
        if (t + 2 < NT) asm volatile("s_waitcnt vmcnt(8)" ::: "memory");
        else            asm volatile("s_waitcnt vmcnt(0)" ::: "memory");
        __builtin_amdgcn_s_barrier();
        __builtin_amdgcn_sched_barrier(0);

        tile_body(t + 1, As1, Bs1, 1);
        if (t + 2 < NT) {
            // boundary after odd tile t+1: need tile t+2 landed;
            // younger VMEM = tile t+3's 8 loads (if staged).
            if (t + 3 < NT) asm volatile("s_waitcnt vmcnt(8)" ::: "memory");
            else            asm volatile("s_waitcnt vmcnt(0)" ::: "memory");
            __builtin_amdgcn_s_barrier();
            __builtin_amdgcn_sched_barrier(0);
        }
    }

    // --- epilogue: 32x32 C/D layout col=lane&31, row=(reg&3)+8*(reg>>2)+4*(lane>>5)
    const int cmb = block_m + wm * 128 + 4 * lh;
    const int cnb = block_n + wn * 64 + ln31;
#pragma unroll
    for (int j = 0; j < 2; ++j) {
        const float bj = bias[cnb + j * 32];
#pragma unroll
        for (int i = 0; i < 4; ++i) {
#pragma unroll
            for (int r = 0; r < 16; ++r) {
                const int row = cmb + i * 32 + (r & 3) + 8 * (r >> 2);
                C[(size_t)row * COUT + (cnb + j * 32)] = acc[i][j][r] + bj;
            }
        }
    }
}

// ---------------------------------------------------------------------------
extern "C" void kernel_launch(void* const* d_in, const int* in_sizes, int n_in,
                              void* d_out, int out_size, void* d_ws, size_t ws_size,
                              hipStream_t stream) {
    const float* x    = (const float*)d_in[0];   // NROWS x KDIM
    const float* w    = (const float*)d_in[1];   // COUT  x KDIM
    const float* bias = (const float*)d_in[2];   // COUT
    float* out = (float*)d_out;

    // workspace layout: xb (134.2 MB) | wb (33.6 MB)
    short* xb = (short*)d_ws;
    short* wb = xb + (size_t)NROWS * KDIM;

    const int n4_x = NROWS * (KDIM / 4);   // 16777216
    const int n4_w = COUT  * (KDIM / 4);   // 4194304

    cvt_f32_to_bf16<<<n4_x / 256, 256, 0, stream>>>(
        (const float4*)x, (uint2*)xb, n4_x);
    cvt_f32_to_bf16<<<n4_w / 256, 256, 0, stream>>>(
        (const float4*)w, (uint2*)wb, n4_w);

    dim3 grid(NBLK);   // 1024 blocks of 512 threads
    gemm_bt_bf16_8ph<<<grid, 512, 0, stream>>>(xb, wb, bias, out);
}